// Round 2
// 352.292 us; speedup vs baseline: 1.0392x; 1.0392x over previous
//
#include <hip/hip_runtime.h>
#include <hip/hip_bf16.h>
#include <stdint.h>

#define MDIM 4096
#define NDIM 4096
#define KDIM 4096

typedef float f32x4 __attribute__((ext_vector_type(4)));
typedef __bf16 bf16x8 __attribute__((ext_vector_type(8)));
typedef short s16x8 __attribute__((ext_vector_type(8)));

// Packed fragment-order layout for a 4096x4096 bf16 operand P[row][k]:
//   band b = row>>7, ktile t = k>>5, frag f = (row&127)>>4,
//   lane = ((k>>3)&3)*16 + (row&15), j = k&7
//   short index = ((((b*128 + t)*8 + f)*64) + lane)*8 + j
// One frag = 1KB contiguous => wave reads contiguous in global AND LDS.

__device__ __forceinline__ unsigned short f2bf(float x) {
  union { float f; unsigned u; } v; v.f = x;
  return (unsigned short)((v.u + 0x7fffu + ((v.u >> 16) & 1u)) >> 16);
}
__device__ __forceinline__ float bf2f(unsigned short b) {
  union { unsigned u; float f; } v; v.u = ((unsigned)b) << 16;
  return v.f;
}

// ---- packed-bf16 atomic add with SFINAE fallback to CAS loop ----
__device__ __forceinline__ void cas_add_bf16(unsigned short* addr2, unsigned short bits, int hi) {
  unsigned* word = (unsigned*)addr2;
  unsigned shift = hi ? 16u : 0u;
  float v = bf2f(bits);
  unsigned old = *word, assumed;
  do {
    assumed = old;
    unsigned short cur = (unsigned short)(assumed >> shift);
    unsigned short upd = f2bf(bf2f(cur) + v);
    unsigned next = (assumed & ~(0xffffu << shift)) | ((unsigned)upd << shift);
    if (next == assumed) break;
    old = atomicCAS(word, assumed, next);
  } while (old != assumed);
}

template <typename T>
__device__ __forceinline__ auto pk_add_impl(T* p, T v, int)
    -> decltype(unsafeAtomicAdd(p, v), void()) {
  unsafeAtomicAdd(p, v);
}
template <typename T>
__device__ __forceinline__ void pk_add_impl(T* p, T v, long) {
  union { T t; unsigned u; } c; c.t = v;
  unsigned short lo = (unsigned short)(c.u & 0xffffu);
  unsigned short hi16 = (unsigned short)(c.u >> 16);
  if (lo) cas_add_bf16((unsigned short*)p, lo, 0);
  if (hi16) cas_add_bf16((unsigned short*)p, hi16, 1);
}

__device__ __forceinline__ void atomic_bf16_add(unsigned short* base2, unsigned short bits, int hi) {
  __hip_bfloat162_raw raw;
  raw.x = hi ? (unsigned short)0 : bits;
  raw.y = hi ? bits : (unsigned short)0;
  __hip_bfloat162 v(raw);
  pk_add_impl((__hip_bfloat162*)base2, v, 0);
}

// ---- fused prep: blocks [0, scBlocks) scatter COO; rest pack x ----
__global__ __launch_bounds__(256) void prep_kernel(const int* __restrict__ rows,
                                                   const int* __restrict__ cols,
                                                   const float* __restrict__ vals, int nnz,
                                                   int scBlocks,
                                                   unsigned short* __restrict__ Wpk,
                                                   const float* __restrict__ x,
                                                   short* __restrict__ Xpk) {
  int b = blockIdx.x, tid = threadIdx.x;
  if (b < scBlocks) {
    int i = b * 256 + tid;
    if (i >= nnz) return;
    int m = rows[i], k = cols[i];
    unsigned short bits = f2bf(vals[i]);
    size_t chunk = ((((size_t)(m >> 7) * 128 + (k >> 5)) * 8 + ((m >> 4) & 7)) * 64) +
                   (((k >> 3) & 3) * 16 + (m & 15));
    size_t idx = chunk * 8 + (k & 7);
    atomic_bf16_add(&Wpk[idx & ~(size_t)1], bits, (int)(idx & 1));
  } else {
    __shared__ float tile[32 * 65];
    int pb = b - scBlocks;
    int n0 = (pb & 63) * 64, k0 = (pb >> 6) * 32;
#pragma unroll
    for (int r = 0; r < 8; r++) {
      int elem = r * 256 + tid;
      int kk = elem >> 6, nn = elem & 63;
      tile[kk * 65 + nn] = x[(size_t)(k0 + kk) * NDIM + n0 + nn];
    }
    __syncthreads();
    int region = tid >> 6, lane = tid & 63;
    int kh = lane >> 4, nl = region * 16 + (lane & 15);
    s16x8 v;
#pragma unroll
    for (int j = 0; j < 8; j++) v[j] = (short)f2bf(tile[(kh * 8 + j) * 65 + nl]);
    int f = ((n0 & 127) >> 4) + region;
    size_t chunk = (((size_t)(n0 >> 7) * 128 + (k0 >> 5)) * 8 + f) * 64 + lane;
    *(s16x8*)&Xpk[chunk * 8] = v;
  }
}

// ---- 256x256-tile 8-wave MFMA GEMM, 4-deep LDS ring, counted vmcnt ----
// Structure per guide T3+T4+T5: two 16-MFMA phases per K-step (BK=32), staging
// issues interleaved between phases, vmcnt(10) keeps 3 K-tiles in flight
// (never drains to 0 in the main loop), setprio(1) around MFMA clusters.
// Packed fragment layout => all LDS traffic contiguous per wave (0 bank conflicts),
// so no XOR swizzle (T2) is needed.

#define GLOAD16(gp, lp)                                              \
  __builtin_amdgcn_global_load_lds(                                  \
      (const __attribute__((address_space(1))) void*)(gp),           \
      (__attribute__((address_space(3))) void*)(lp), 16, 0, 0)

__global__ __launch_bounds__(512, 2) void gemm_kernel(const short* __restrict__ A,
                                                      const short* __restrict__ Bt,
                                                      const float* __restrict__ bias,
                                                      float* __restrict__ C) {
  // 4 ring buffers x 16 chunks x 512 shorts (1KB) = 16KB per operand per buf;
  // total LDS = 2 * 4 * 16KB = 128KB -> 1 block/CU, 8 waves.
  __shared__ __align__(16) short sA[4][8192];
  __shared__ __align__(16) short sB[4][8192];

  int tid = threadIdx.x, lane = tid & 63, w = tid >> 6;
  int wr = w >> 2, wc = w & 3;              // 2 (M) x 4 (N) wave grid
  int m16 = lane & 15, quad = lane >> 4;
  int by = blockIdx.y, bx = blockIdx.x;

  f32x4 acc[8][4];
#pragma unroll
  for (int i = 0; i < 8; i++)
#pragma unroll
    for (int j = 0; j < 4; j++) acc[i][j] = f32x4{0.f, 0.f, 0.f, 0.f};

  // Staging: per K-tile the A-tile is 16 chunks (band-half s=0/1, frag f=w).
  // Wave w stages chunk s*8+w of each operand; 4 gload_lds per thread per tile.
  const short* aSrc[2];
  const short* bSrc[2];
  int ldsOff[2];
#pragma unroll
  for (int s = 0; s < 2; s++) {
    aSrc[s] = A + ((size_t)(2 * by + s) * 128 * 8 + w) * 512 + lane * 8;
    bSrc[s] = Bt + ((size_t)(2 * bx + s) * 128 * 8 + w) * 512 + lane * 8;
    ldsOff[s] = (s * 8 + w) * 512 + lane * 8;
  }
  // K-tile stride in shorts: 8 frags * 512 = 4096.

  // Prologue: stage tiles 0,1,2 into bufs 0,1,2 (order A,A,B,B per tile —
  // vmcnt accounting below depends on 4 loads per tile in issue order).
#pragma unroll
  for (int t = 0; t < 3; t++) {
    GLOAD16(aSrc[0] + (size_t)t * 4096, &sA[t][ldsOff[0]]);
    GLOAD16(aSrc[1] + (size_t)t * 4096, &sA[t][ldsOff[1]]);
    GLOAD16(bSrc[0] + (size_t)t * 4096, &sB[t][ldsOff[0]]);
    GLOAD16(bSrc[1] + (size_t)t * 4096, &sB[t][ldsOff[1]]);
  }

  for (int t = 0; t < 128; t++) {
    int buf = t & 3;
    int nbuf = (t + 3) & 3;
    size_t tn = (size_t)((t + 3) & 127) * 4096;  // wrap prefetch stays in-bounds

    // issue A-half of tile t+3, then wait for tile t's 4 loads (oldest):
    // outstanding <= A(t),B(t),A(t+1),B(t+1),A(t+2),B(t+2),A(t+3) = 14 -> vmcnt(10)
    GLOAD16(aSrc[0] + tn, &sA[nbuf][ldsOff[0]]);
    GLOAD16(aSrc[1] + tn, &sA[nbuf][ldsOff[1]]);
    __builtin_amdgcn_s_waitcnt(0x0F7A);  // vmcnt(10) — tile t resident, 10 in flight
    __builtin_amdgcn_s_barrier();

    const short* pA = &sA[buf][0];
    const short* pB = &sB[buf][0];
    bf16x8 a[8], b[4];

    // phase A: top M-half (mi 0..3) x all N — 8 ds_read_b128, 16 MFMA
#pragma unroll
    for (int mi = 0; mi < 4; mi++)
      a[mi] = *(const bf16x8*)&pA[(wr * 8 + mi) * 512 + lane * 8];
#pragma unroll
    for (int nj = 0; nj < 4; nj++)
      b[nj] = *(const bf16x8*)&pB[((wc >> 1) * 8 + (wc & 1) * 4 + nj) * 512 + lane * 8];
    __builtin_amdgcn_s_setprio(1);
#pragma unroll
    for (int mi = 0; mi < 4; mi++)
#pragma unroll
      for (int nj = 0; nj < 4; nj++)
        acc[mi][nj] = __builtin_amdgcn_mfma_f32_16x16x32_bf16(a[mi], b[nj], acc[mi][nj], 0, 0, 0);
    __builtin_amdgcn_s_setprio(0);

    // phase B: issue B-half of tile t+3, bottom M-half (mi 4..7) — 4 ds_read, 16 MFMA
    GLOAD16(bSrc[0] + tn, &sB[nbuf][ldsOff[0]]);
    GLOAD16(bSrc[1] + tn, &sB[nbuf][ldsOff[1]]);
#pragma unroll
    for (int mi = 4; mi < 8; mi++)
      a[mi] = *(const bf16x8*)&pA[(wr * 8 + mi) * 512 + lane * 8];
    __builtin_amdgcn_s_setprio(1);
#pragma unroll
    for (int mi = 4; mi < 8; mi++)
#pragma unroll
      for (int nj = 0; nj < 4; nj++)
        acc[mi][nj] = __builtin_amdgcn_mfma_f32_16x16x32_bf16(a[mi], b[nj], acc[mi][nj], 0, 0, 0);
    __builtin_amdgcn_s_setprio(0);
    __builtin_amdgcn_s_barrier();  // all reads of buf done before it is restaged
  }
  __builtin_amdgcn_s_waitcnt(0x0F70);  // vmcnt(0): drain wrap prefetch

  // Epilogue: C = acc + bias
#pragma unroll
  for (int nj = 0; nj < 4; nj++) {
    int col = bx * 256 + wc * 64 + nj * 16 + m16;
    float bv = bias[col];
#pragma unroll
    for (int mi = 0; mi < 8; mi++) {
      int row0 = by * 256 + wr * 128 + mi * 16 + quad * 4;
      f32x4 v = acc[mi][nj];
#pragma unroll
      for (int r = 0; r < 4; r++) C[(size_t)(row0 + r) * NDIM + col] = v[r] + bv;
    }
  }
}

extern "C" void kernel_launch(void* const* d_in, const int* in_sizes, int n_in,
                              void* d_out, int out_size, void* d_ws, size_t ws_size,
                              hipStream_t stream) {
  const float* x = (const float*)d_in[0];
  const int* rows = (const int*)d_in[1];
  const int* cols = (const int*)d_in[2];
  const float* vals = (const float*)d_in[3];
  const float* bias = (const float*)d_in[4];
  int nnz = in_sizes[1];
  float* y = (float*)d_out;

  char* ws = (char*)d_ws;
  unsigned short* Wpk = (unsigned short*)ws;
  short* Xpk = (short*)(ws + (32u << 20));

  int scBlocks = (nnz + 255) / 256;
  int pxBlocks = (NDIM / 64) * (KDIM / 32);  // 8192

  hipMemsetAsync(Wpk, 0, (size_t)MDIM * KDIM * sizeof(short), stream);
  prep_kernel<<<scBlocks + pxBlocks, 256, 0, stream>>>(rows, cols, vals, nnz, scBlocks,
                                                       Wpk, x, Xpk);
  gemm_kernel<<<dim3(NDIM / 256, MDIM / 256), 512, 0, stream>>>((const short*)Wpk, Xpk, bias, y);
}

// Round 3
// 328.968 us; speedup vs baseline: 1.1129x; 1.0709x over previous
//
#include <hip/hip_runtime.h>
#include <hip/hip_bf16.h>
#include <stdint.h>

#define MDIM 4096
#define NDIM 4096
#define KDIM 4096

typedef float f32x4 __attribute__((ext_vector_type(4)));
typedef __bf16 bf16x8 __attribute__((ext_vector_type(8)));
typedef short s16x8 __attribute__((ext_vector_type(8)));

// Packed fragment-order layout for a 4096x4096 bf16 operand P[row][k]:
//   band b = row>>7, ktile t = k>>5, frag f = (row&127)>>4,
//   lane = ((k>>3)&3)*16 + (row&15), j = k&7
//   short index = ((((b*128 + t)*8 + f)*64) + lane)*8 + j
// One frag = 1KB contiguous => wave reads contiguous in global AND LDS.

__device__ __forceinline__ unsigned short f2bf(float x) {
  union { float f; unsigned u; } v; v.f = x;
  return (unsigned short)((v.u + 0x7fffu + ((v.u >> 16) & 1u)) >> 16);
}
__device__ __forceinline__ float bf2f(unsigned short b) {
  union { unsigned u; float f; } v; v.u = ((unsigned)b) << 16;
  return v.f;
}

// ---- packed-bf16 atomic add with SFINAE fallback to CAS loop ----
__device__ __forceinline__ void cas_add_bf16(unsigned short* addr2, unsigned short bits, int hi) {
  unsigned* word = (unsigned*)addr2;
  unsigned shift = hi ? 16u : 0u;
  float v = bf2f(bits);
  unsigned old = *word, assumed;
  do {
    assumed = old;
    unsigned short cur = (unsigned short)(assumed >> shift);
    unsigned short upd = f2bf(bf2f(cur) + v);
    unsigned next = (assumed & ~(0xffffu << shift)) | ((unsigned)upd << shift);
    if (next == assumed) break;
    old = atomicCAS(word, assumed, next);
  } while (old != assumed);
}

template <typename T>
__device__ __forceinline__ auto pk_add_impl(T* p, T v, int)
    -> decltype(unsafeAtomicAdd(p, v), void()) {
  unsafeAtomicAdd(p, v);
}
template <typename T>
__device__ __forceinline__ void pk_add_impl(T* p, T v, long) {
  union { T t; unsigned u; } c; c.t = v;
  unsigned short lo = (unsigned short)(c.u & 0xffffu);
  unsigned short hi16 = (unsigned short)(c.u >> 16);
  if (lo) cas_add_bf16((unsigned short*)p, lo, 0);
  if (hi16) cas_add_bf16((unsigned short*)p, hi16, 1);
}

__device__ __forceinline__ void atomic_bf16_add(unsigned short* base2, unsigned short bits, int hi) {
  __hip_bfloat162_raw raw;
  raw.x = hi ? (unsigned short)0 : bits;
  raw.y = hi ? bits : (unsigned short)0;
  __hip_bfloat162 v(raw);
  pk_add_impl((__hip_bfloat162*)base2, v, 0);
}

// ---- fused prep: blocks [0, scBlocks) scatter COO; rest pack x ----
__global__ __launch_bounds__(256) void prep_kernel(const int* __restrict__ rows,
                                                   const int* __restrict__ cols,
                                                   const float* __restrict__ vals, int nnz,
                                                   int scBlocks,
                                                   unsigned short* __restrict__ Wpk,
                                                   const float* __restrict__ x,
                                                   short* __restrict__ Xpk) {
  int b = blockIdx.x, tid = threadIdx.x;
  if (b < scBlocks) {
    int i = b * 256 + tid;
    if (i >= nnz) return;
    int m = rows[i], k = cols[i];
    unsigned short bits = f2bf(vals[i]);
    size_t chunk = ((((size_t)(m >> 7) * 128 + (k >> 5)) * 8 + ((m >> 4) & 7)) * 64) +
                   (((k >> 3) & 3) * 16 + (m & 15));
    size_t idx = chunk * 8 + (k & 7);
    atomic_bf16_add(&Wpk[idx & ~(size_t)1], bits, (int)(idx & 1));
  } else {
    __shared__ float tile[32 * 65];
    int pb = b - scBlocks;
    int n0 = (pb & 63) * 64, k0 = (pb >> 6) * 32;
#pragma unroll
    for (int r = 0; r < 8; r++) {
      int elem = r * 256 + tid;
      int kk = elem >> 6, nn = elem & 63;
      tile[kk * 65 + nn] = x[(size_t)(k0 + kk) * NDIM + n0 + nn];
    }
    __syncthreads();
    int region = tid >> 6, lane = tid & 63;
    int kh = lane >> 4, nl = region * 16 + (lane & 15);
    s16x8 v;
#pragma unroll
    for (int j = 0; j < 8; j++) v[j] = (short)f2bf(tile[(kh * 8 + j) * 65 + nl]);
    int f = ((n0 & 127) >> 4) + region;
    size_t chunk = (((size_t)(n0 >> 7) * 128 + (k0 >> 5)) * 8 + f) * 64 + lane;
    *(s16x8*)&Xpk[chunk * 8] = v;
  }
}

// ---- 256x256-tile 8-wave MFMA GEMM, 4-deep ring, m201-style phase interleave ----
// Per iteration (K=32): 12 ds_reads issued BEFORE the alignment barrier (latency
// hides under barrier wait), A-half staging before barrier, MFMA cluster 1 (16),
// B-half staging, MFMA cluster 2 (16), counted vmcnt(8) (retires tile t+1's 4
// loads; never 0 in-loop), end barrier. setprio(1) around each MFMA cluster.
// Packed fragment layout => all LDS traffic contiguous per wave (0 bank conflicts).

#define GLOAD16(gp, lp)                                              \
  __builtin_amdgcn_global_load_lds(                                  \
      (const __attribute__((address_space(1))) void*)(gp),           \
      (__attribute__((address_space(3))) void*)(lp), 16, 0, 0)

__global__ __launch_bounds__(512, 2) void gemm_kernel(const short* __restrict__ A,
                                                      const short* __restrict__ Bt,
                                                      const float* __restrict__ bias,
                                                      float* __restrict__ C) {
  // 4 ring buffers x 16 chunks x 512 shorts (1KB) = 16KB per operand per buf;
  // total LDS = 2 * 4 * 16KB = 128KB -> 1 block/CU, 8 waves.
  __shared__ __align__(16) short sA[4][8192];
  __shared__ __align__(16) short sB[4][8192];

  int tid = threadIdx.x, lane = tid & 63, w = tid >> 6;
  int wr = w >> 2, wc = w & 3;              // 2 (M) x 4 (N) wave grid
  int m16 = lane & 15, quad = lane >> 4;
  int by = blockIdx.y, bx = blockIdx.x;

  f32x4 acc[8][4];
#pragma unroll
  for (int i = 0; i < 8; i++)
#pragma unroll
    for (int j = 0; j < 4; j++) acc[i][j] = f32x4{0.f, 0.f, 0.f, 0.f};

  // Staging: per K-tile (K=32) the A-tile is 16 chunks (band-half s=0/1, frag w).
  // Wave w stages chunk s*8+w of each operand; 4 gload_lds per thread per tile.
  const short* aSrc[2];
  const short* bSrc[2];
  int ldsOff[2];
#pragma unroll
  for (int s = 0; s < 2; s++) {
    aSrc[s] = A + ((size_t)(2 * by + s) * 128 * 8 + w) * 512 + lane * 8;
    bSrc[s] = Bt + ((size_t)(2 * bx + s) * 128 * 8 + w) * 512 + lane * 8;
    ldsOff[s] = (s * 8 + w) * 512 + lane * 8;
  }
  // K-tile stride in shorts: 8 frags * 512 = 4096.

  // Prologue: stage tiles 0,1,2 into bufs 0,1,2 (order A,A,B,B per tile —
  // the vmcnt ledger depends on 4 loads per tile in this issue order).
#pragma unroll
  for (int t = 0; t < 3; t++) {
    GLOAD16(aSrc[0] + (size_t)t * 4096, &sA[t][ldsOff[0]]);
    GLOAD16(aSrc[1] + (size_t)t * 4096, &sA[t][ldsOff[1]]);
    GLOAD16(bSrc[0] + (size_t)t * 4096, &sB[t][ldsOff[0]]);
    GLOAD16(bSrc[1] + (size_t)t * 4096, &sB[t][ldsOff[1]]);
  }
  // Tile 0 resident before first ds_read: retire its 4 loads, keep 8 in flight.
  __builtin_amdgcn_s_waitcnt(0x0F78);  // vmcnt(8)
  __builtin_amdgcn_s_barrier();

  for (int t = 0; t < 128; t++) {
    int buf = t & 3;
    int nbuf = (t + 3) & 3;
    size_t tn = (size_t)((t + 3) & 127) * 4096;  // wrap prefetch stays in-bounds

    const short* pA = &sA[buf][0];
    const short* pB = &sB[buf][0];
    bf16x8 a[4], b[4], a2[4];

    // --- issue all 12 ds_reads up front: latency hides under the barrier ---
#pragma unroll
    for (int mi = 0; mi < 4; mi++)
      a[mi] = *(const bf16x8*)&pA[(wr * 8 + mi) * 512 + lane * 8];
#pragma unroll
    for (int nj = 0; nj < 4; nj++)
      b[nj] = *(const bf16x8*)&pB[((wc >> 1) * 8 + (wc & 1) * 4 + nj) * 512 + lane * 8];
#pragma unroll
    for (int mi = 0; mi < 4; mi++)
      a2[mi] = *(const bf16x8*)&pA[(wr * 8 + 4 + mi) * 512 + lane * 8];

    // stage A-half of tile t+3 into buf (t-1)&3 (its readers done last iter)
    GLOAD16(aSrc[0] + tn, &sA[nbuf][ldsOff[0]]);
    GLOAD16(aSrc[1] + tn, &sA[nbuf][ldsOff[1]]);
    __builtin_amdgcn_s_barrier();  // alignment: MFMA clusters coincide across waves

    // phase A: mi 0..3 x nj 0..3 (compiler emits counted lgkmcnt from deps)
    __builtin_amdgcn_s_setprio(1);
#pragma unroll
    for (int mi = 0; mi < 4; mi++)
#pragma unroll
      for (int nj = 0; nj < 4; nj++)
        acc[mi][nj] = __builtin_amdgcn_mfma_f32_16x16x32_bf16(a[mi], b[nj], acc[mi][nj], 0, 0, 0);
    __builtin_amdgcn_s_setprio(0);

    // stage B-half of tile t+3 between the MFMA clusters
    GLOAD16(bSrc[0] + tn, &sB[nbuf][ldsOff[0]]);
    GLOAD16(bSrc[1] + tn, &sB[nbuf][ldsOff[1]]);

    // phase B: mi 4..7 x nj 0..3 (b[] stays register-resident)
    __builtin_amdgcn_s_setprio(1);
#pragma unroll
    for (int mi = 0; mi < 4; mi++)
#pragma unroll
      for (int nj = 0; nj < 4; nj++)
        acc[4 + mi][nj] = __builtin_amdgcn_mfma_f32_16x16x32_bf16(a2[mi], b[nj], acc[4 + mi][nj], 0, 0, 0);
    __builtin_amdgcn_s_setprio(0);

    // retire tile t+1's 4 loads (oldest); 8 stay in flight — never drains to 0.
    // ledger: start-of-iter 8 outstanding {t+2,t+3}... wait counts own-wave ops;
    // +4 issued this iter = 12; vmcnt(8) retires exactly tile t+1's 4.
    __builtin_amdgcn_s_waitcnt(0x0F78);  // vmcnt(8)
    __builtin_amdgcn_s_barrier();
  }
  __builtin_amdgcn_s_waitcnt(0x0F70);  // vmcnt(0): drain wrap prefetch

  // Epilogue: C = acc + bias
#pragma unroll
  for (int nj = 0; nj < 4; nj++) {
    int col = bx * 256 + wc * 64 + nj * 16 + m16;
    float bv = bias[col];
#pragma unroll
    for (int mi = 0; mi < 8; mi++) {
      int row0 = by * 256 + wr * 128 + mi * 16 + quad * 4;
      f32x4 v = acc[mi][nj];
#pragma unroll
      for (int r = 0; r < 4; r++) C[(size_t)(row0 + r) * NDIM + col] = v[r] + bv;
    }
  }
}

extern "C" void kernel_launch(void* const* d_in, const int* in_sizes, int n_in,
                              void* d_out, int out_size, void* d_ws, size_t ws_size,
                              hipStream_t stream) {
  const float* x = (const float*)d_in[0];
  const int* rows = (const int*)d_in[1];
  const int* cols = (const int*)d_in[2];
  const float* vals = (const float*)d_in[3];
  const float* bias = (const float*)d_in[4];
  int nnz = in_sizes[1];
  float* y = (float*)d_out;

  char* ws = (char*)d_ws;
  unsigned short* Wpk = (unsigned short*)ws;
  short* Xpk = (short*)(ws + (32u << 20));

  int scBlocks = (nnz + 255) / 256;
  int pxBlocks = (NDIM / 64) * (KDIM / 32);  // 8192

  hipMemsetAsync(Wpk, 0, (size_t)MDIM * KDIM * sizeof(short), stream);
  prep_kernel<<<scBlocks + pxBlocks, 256, 0, stream>>>(rows, cols, vals, nnz, scBlocks,
                                                       Wpk, x, Xpk);
  gemm_kernel<<<dim3(NDIM / 256, MDIM / 256), 512, 0, stream>>>((const short*)Wpk, Xpk, bias, y);
}